// Round 2
// baseline (68.792 us; speedup 1.0000x reference)
//
#include <hip/hip_runtime.h>
#include <hip/hip_bf16.h>

// out[i][j][o] = sum_h X[i+1][h] * X[j+1][h] * W[o][h] + b[o]
// (diff/W2 term cancels under symmetrization; only W[:, :768] is live)
//
// Two-kernel design:
//  A) prep: P0 = bf16(X .* w0), P1 = bf16(X .* w1), PX = bf16(X) -> workspace.
//     Removes the 16x-redundant per-block multiply/convert of previous rounds.
//  B) gemm: MFMA fragments loaded DIRECTLY from global (2.25 MB, L2-resident,
//     XCD-swizzled) - no LDS operand staging, no staging barriers.
//     16 waves/block = 4 waves/SIMD; 4 output quadrants x 4-way K-split;
//     26 KB LDS used only for the K-split reduction.
// X: (512, 768) fp32, W: (2, 1536) fp32, b: (2,) fp32, out: (510, 510, 2) fp32

constexpr int H  = 768;
constexpr int M  = 510;
constexpr int NP = 512 * 768;       // elems per P array

typedef __attribute__((ext_vector_type(8))) short short8;   // 8 bf16 = 4 VGPRs
typedef __attribute__((ext_vector_type(4))) float f32x4;

__device__ inline float4 mul4(float4 a, float4 b) {
  return make_float4(a.x * b.x, a.y * b.y, a.z * b.z, a.w * b.w);
}

__device__ inline unsigned int cvt2(float a, float b) {
  __hip_bfloat162 p = __float22bfloat162_rn(make_float2(a, b));  // packed RNE
  return *(unsigned int*)&p;
}

__device__ inline uint4 cvt8(float4 a, float4 b) {
  uint4 u;
  u.x = cvt2(a.x, a.y);
  u.y = cvt2(a.z, a.w);
  u.z = cvt2(b.x, b.y);
  u.w = cvt2(b.z, b.w);
  return u;
}

// ---------------- Kernel A: prep (one pass over X) ----------------
__global__ __launch_bounds__(256, 1) void prep_kernel(
    const float* __restrict__ X, const float* __restrict__ W,
    unsigned short* __restrict__ P) {
  const int t  = blockIdx.x * 256 + threadIdx.x;  // 0..49151
  const int e0 = t * 8;                           // 8 elems/thread
  const int h  = e0 % H;                          // 768 % 8 == 0: contiguous
  float4 x0  = *(const float4*)(X + e0);
  float4 x1  = *(const float4*)(X + e0 + 4);
  float4 w00 = *(const float4*)(W + h);
  float4 w01 = *(const float4*)(W + h + 4);
  float4 w10 = *(const float4*)(W + 1536 + h);
  float4 w11 = *(const float4*)(W + 1536 + h + 4);
  *(uint4*)(P + e0)          = cvt8(mul4(x0, w00), mul4(x1, w01));  // P0
  *(uint4*)(P + NP + e0)     = cvt8(mul4(x0, w10), mul4(x1, w11));  // P1
  *(uint4*)(P + 2 * NP + e0) = cvt8(x0, x1);                        // PX
}

// ---------------- Kernel B: register-direct MFMA GEMM ----------------
__global__ __launch_bounds__(1024, 1) void pairwise_head_mfma(
    const unsigned short* __restrict__ P, const float* __restrict__ bias,
    float* __restrict__ out) {
  // XCD-aware swizzle: 256 blocks, 8 XCDs -> each XCD owns 32 consecutive
  // logical tiles (2 full i-panel rows) for L2 panel locality. 256%8==0.
  const int bid = blockIdx.x;
  const int sb  = (bid & 7) * 32 + (bid >> 3);
  const int gj0 = (sb & 15) * 32;
  const int gi0 = (sb >> 4) * 32;

  const int tid  = threadIdx.x;
  const int wave = tid >> 6;     // 0..15
  const int lane = tid & 63;
  const int lo = lane & 15;      // frag row (A) / col (B)
  const int q  = lane >> 4;      // quad -> k-subgroup
  const int quad = wave & 3;     // output quadrant
  const int kh   = wave >> 2;    // K-split: [kh*192, +192)
  const int mi = quad >> 1;
  const int nj = quad & 1;

  int ar = gi0 + 1 + mi * 16 + lo; if (ar > 511) ar = 511;  // clamp; masked out
  int br = gj0 + 1 + nj * 16 + lo; if (br > 511) br = 511;
  const int kb = kh * 192 + q * 8;
  const unsigned short* pa0 = P          + ar * H + kb;
  const unsigned short* pa1 = P + NP     + ar * H + kb;
  const unsigned short* pb  = P + 2 * NP + br * H + kb;

  f32x4 acc0 = {0.f, 0.f, 0.f, 0.f};
  f32x4 acc1 = {0.f, 0.f, 0.f, 0.f};
#pragma unroll
  for (int c = 0; c < 6; ++c) {   // 6 chunks of K=32 per K-quarter
    const short8 a0 = *(const short8*)(pa0 + c * 32);
    const short8 a1 = *(const short8*)(pa1 + c * 32);
    const short8 b  = *(const short8*)(pb  + c * 32);
    acc0 = __builtin_amdgcn_mfma_f32_16x16x32_bf16(a0, b, acc0, 0, 0, 0);
    acc1 = __builtin_amdgcn_mfma_f32_16x16x32_bf16(a1, b, acc1, 0, 0, 0);
  }

  // ---- 4-way K reduction through LDS ----
  // red[slab=kh-1][quad][16 rows][17 float2-slots]; pad 17 rotates banks
  __shared__ __align__(16) float red[3 * 4 * 16 * 17 * 2];  // 26,112 B
  if (kh > 0) {
#pragma unroll
    for (int r = 0; r < 4; ++r) {
      const int idx = (((kh - 1) * 4 + quad) * 16 + q * 4 + r) * 17 + lo;
      *(float2*)(red + idx * 2) = make_float2(acc0[r], acc1[r]);
    }
  }
  __syncthreads();

  // ---- epilogue (kh=0 waves): add 3 partner partials + bias, store ----
  // D layout col=lane&15, row=q*4+reg (proven in prior rounds)
  if (kh == 0) {
    const float b0 = bias[0];
    const float b1 = bias[1];
    const int j  = gj0 + nj * 16 + lo;
    const int i0 = gi0 + mi * 16 + q * 4;
    if (j < M) {
#pragma unroll
      for (int r = 0; r < 4; ++r) {
        const int i = i0 + r;
        if (i < M) {
          float s0 = acc0[r] + b0;
          float s1 = acc1[r] + b1;
#pragma unroll
          for (int s = 0; s < 3; ++s) {
            const int idx = ((s * 4 + quad) * 16 + q * 4 + r) * 17 + lo;
            const float2 p = *(const float2*)(red + idx * 2);
            s0 += p.x;
            s1 += p.y;
          }
          *(float2*)(out + ((size_t)i * M + j) * 2) = make_float2(s0, s1);
        }
      }
    }
  }
}

extern "C" void kernel_launch(void* const* d_in, const int* in_sizes, int n_in,
                              void* d_out, int out_size, void* d_ws, size_t ws_size,
                              hipStream_t stream) {
  const float* X    = (const float*)d_in[0];  // (1, 512, 768)
  const float* W    = (const float*)d_in[1];  // (2, 1536)
  const float* bias = (const float*)d_in[2];  // (2,)
  float* out = (float*)d_out;                 // (510, 510, 2)
  unsigned short* P = (unsigned short*)d_ws;  // 3 x 512x768 bf16 = 2.25 MB

  hipLaunchKernelGGL(prep_kernel, dim3(192), dim3(256), 0, stream, X, W, P);
  hipLaunchKernelGGL(pairwise_head_mfma, dim3(256), dim3(1024), 0, stream,
                     P, bias, out);
}

// Round 3
// 62.222 us; speedup vs baseline: 1.1056x; 1.1056x over previous
//
#include <hip/hip_runtime.h>
#include <hip/hip_bf16.h>

// out[i][j][o] = sum_h X[i+1][h] * X[j+1][h] * W[o][h] + b[o]
// (diff/W2 term cancels under symmetrization; only W[:, :768] is live)
//
// Single kernel (round-2 lesson: every extra dispatch costs ~3+ us).
// Single-shot LDS staging of all three K=768 tiles (145.5 KB), 512 thr = 8 waves.
// This round: load/store-separated staging (24 float4 in flight),
// 16B ds_writes (18 vs 36 stores), compact 4x8-tile-per-XCD swizzle.
// X: (512, 768) fp32, W: (2, 1536) fp32, b: (2,) fp32, out: (510, 510, 2) fp32

constexpr int H   = 768;
constexpr int M   = 510;
constexpr int LDP = H + 8;   // 776 elems = 1552 B row stride: 4-bank rotation,
                             // 16B-aligned rows; ds_read lo-lanes 2-way = free

typedef __attribute__((ext_vector_type(8))) short short8;   // 8 bf16 = 4 VGPRs
typedef __attribute__((ext_vector_type(4))) float f32x4;

__device__ inline float4 mul4(float4 a, float4 b) {
  return make_float4(a.x * b.x, a.y * b.y, a.z * b.z, a.w * b.w);
}

__device__ inline unsigned int cvt2(float a, float b) {
  __hip_bfloat162 p = __float22bfloat162_rn(make_float2(a, b));  // packed RNE
  return *(unsigned int*)&p;
}

__device__ inline uint4 cvt8(float4 a, float4 b) {
  uint4 u;
  u.x = cvt2(a.x, a.y);
  u.y = cvt2(a.z, a.w);
  u.z = cvt2(b.x, b.y);
  u.w = cvt2(b.z, b.w);
  return u;
}

__global__ __launch_bounds__(512, 1) void pairwise_head_mfma(
    const float* __restrict__ X, const float* __restrict__ W,
    const float* __restrict__ bias, float* __restrict__ out) {
  __shared__ __align__(16) unsigned short sm[3 * 32 * LDP];  // 148,992 B
  unsigned short* sA0 = sm;                 // rows-i, * w0
  unsigned short* sA1 = sm + 32 * LDP;      // rows-i, * w1
  unsigned short* sB  = sm + 2 * 32 * LDP;  // rows-j, raw

  // ---- compact XCD swizzle: each XCD owns a 4(i) x 8(j) tile chunk ----
  // footprint/XCD: 4 A-panels + 8 B-panels = 384 rows (vs 576 linear)
  const int bid = blockIdx.x;
  const int xcd = bid & 7;
  const int k   = bid >> 3;                  // 0..31 within XCD
  const int gi0 = ((xcd >> 1) * 4 + (k >> 3)) * 32;
  const int gj0 = ((xcd & 1) * 8 + (k & 7)) * 32;

  const int tid = threadIdx.x;
  const float b0 = bias[0];                  // prefetch before staging
  const float b1 = bias[1];

  // ---- staging: 16 threads/row; thread owns 8 contig elems per 128-chunk ----
  const int srow = tid >> 4;    // 0..31
  const int sc   = tid & 15;    // 0..15
  int arow = gi0 + 1 + srow; if (arow > 511) arow = 511;  // clamp; output masked
  int brow = gj0 + 1 + srow; if (brow > 511) brow = 511;
  const float4* Xa = (const float4*)(X + (size_t)arow * H);
  const float4* Xb = (const float4*)(X + (size_t)brow * H);
  const float4* W0 = (const float4*)(W);
  const float4* W1 = (const float4*)(W + 1536);
  unsigned short* a0p = sA0 + srow * LDP + sc * 8;
  unsigned short* a1p = sA1 + srow * LDP + sc * 8;
  unsigned short* bp  = sB  + srow * LDP + sc * 8;

  // two half-batches: all 24 float4 loads of a half issue before any
  // dependent cvt/ds_write (compile-time indices only -> stays in VGPRs)
#pragma unroll
  for (int hf = 0; hf < 2; ++hf) {
    float4 r[3][8];
#pragma unroll
    for (int v = 0; v < 3; ++v) {
      const int c2 = (hf * 3 + v) * 32 + sc * 2;   // float4 idx; +1 = contig
      r[v][0] = Xa[c2]; r[v][1] = Xa[c2 + 1];
      r[v][2] = Xb[c2]; r[v][3] = Xb[c2 + 1];
      r[v][4] = W0[c2]; r[v][5] = W0[c2 + 1];
      r[v][6] = W1[c2]; r[v][7] = W1[c2 + 1];
    }
#pragma unroll
    for (int v = 0; v < 3; ++v) {
      const int off = (hf * 3 + v) * 128;          // elem offset in row
      *(uint4*)(a0p + off) = cvt8(mul4(r[v][0], r[v][4]), mul4(r[v][1], r[v][5]));
      *(uint4*)(a1p + off) = cvt8(mul4(r[v][0], r[v][6]), mul4(r[v][1], r[v][7]));
      *(uint4*)(bp  + off) = cvt8(r[v][2], r[v][3]);
    }
  }
  __syncthreads();

  // ---- compute: 8 waves = 4 quadrants (mi,nj) x 2 K-halves (kh) ----
  const int wave = tid >> 6;
  const int lane = tid & 63;
  const int lo = lane & 15;     // frag row (A) / col (B)
  const int q  = lane >> 4;     // quad -> k-subgroup
  const int quad = wave & 3;
  const int kh   = wave >> 2;   // K-half: [kh*384, +384)
  const int mi = quad >> 1;
  const int nj = quad & 1;
  const unsigned short* pa0 = sA0 + (mi * 16 + lo) * LDP + kh * 384 + q * 8;
  const unsigned short* pa1 = sA1 + (mi * 16 + lo) * LDP + kh * 384 + q * 8;
  const unsigned short* pb  = sB  + (nj * 16 + lo) * LDP + kh * 384 + q * 8;

  f32x4 acc0 = {0.f, 0.f, 0.f, 0.f};
  f32x4 acc1 = {0.f, 0.f, 0.f, 0.f};
#pragma unroll
  for (int c = 0; c < 12; ++c) {        // 12 chunks of K=32 per K-half
    const short8 a0 = *(const short8*)(pa0 + c * 32);
    const short8 a1 = *(const short8*)(pa1 + c * 32);
    const short8 b  = *(const short8*)(pb  + c * 32);
    acc0 = __builtin_amdgcn_mfma_f32_16x16x32_bf16(a0, b, acc0, 0, 0, 0);
    acc1 = __builtin_amdgcn_mfma_f32_16x16x32_bf16(a1, b, acc1, 0, 0, 0);
  }

  __syncthreads();   // all LDS reads done; sm reusable as reduce buffer

  // ---- 2-way K reduction through LDS (aliases sm) ----
  // layout: [quad][16 rows][17 float2-slots] (pad 17 breaks bank alias)
  float* red = (float*)sm;
  if (kh == 1) {
#pragma unroll
    for (int r = 0; r < 4; ++r) {
      const int rl = q * 4 + r;
      float2 v = make_float2(acc0[r], acc1[r]);
      *(float2*)(red + ((quad * 16 + rl) * 17 + lo) * 2) = v;
    }
  }
  __syncthreads();

  // ---- epilogue (kh=0 waves): add partner partial + bias, store ----
  // D layout col=lane&15, row=q*4+reg (proven)
  if (kh == 0) {
    const int j  = gj0 + nj * 16 + lo;
    const int i0 = gi0 + mi * 16 + q * 4;
    if (j < M) {
#pragma unroll
      for (int r = 0; r < 4; ++r) {
        const int i = i0 + r;
        if (i < M) {
          const float2 p =
              *(const float2*)(red + ((quad * 16 + (q * 4 + r)) * 17 + lo) * 2);
          float2 v = make_float2(acc0[r] + p.x + b0, acc1[r] + p.y + b1);
          *(float2*)(out + ((size_t)i * M + j) * 2) = v;  // coalesced 128B/quad
        }
      }
    }
  }
}

extern "C" void kernel_launch(void* const* d_in, const int* in_sizes, int n_in,
                              void* d_out, int out_size, void* d_ws, size_t ws_size,
                              hipStream_t stream) {
  const float* X    = (const float*)d_in[0];  // (1, 512, 768)
  const float* W    = (const float*)d_in[1];  // (2, 1536)
  const float* bias = (const float*)d_in[2];  // (2,)
  float* out = (float*)d_out;                 // (510, 510, 2)

  dim3 grid(256);
  dim3 block(512);
  hipLaunchKernelGGL(pairwise_head_mfma, grid, block, 0, stream,
                     X, W, bias, out);
}